// Round 7
// baseline (644.642 us; speedup 1.0000x reference)
//
#include <hip/hip_runtime.h>

#define NN 4096
#define IN_F 256
#define OUT_F 64
#define K_CH 4
#define ALPHA 0.2f
#define JP 8           // j-partitions per channel in k2 (64*8=512 blocks)
#define JCOLS 512      // NN / JP
#define ROWS1 16       // rows per k1 chunk
#define IC1 256        // NN / ROWS1 chunks per channel

typedef __bf16 bf16;
typedef __attribute__((ext_vector_type(8))) __bf16 bf16x8;
typedef __attribute__((ext_vector_type(4))) float f32x4;

// ---------------- k0: Wh = h@W (fp32) ; Wh1 = Wh@a[:64] ; Wh2 = Wh@a[64:]
__global__ __launch_bounds__(256) void k0_wh(const float* __restrict__ h,
                                             const float* __restrict__ W,
                                             const float* __restrict__ a,
                                             float* __restrict__ Wh,
                                             float* __restrict__ Wh1,
                                             float* __restrict__ Wh2) {
    int tid = threadIdx.x;
    int wave = tid >> 6, lane = tid & 63;
    int i = blockIdx.x * 4 + wave;
    const float* hrow = h + (size_t)i * IN_F;
    float acc = 0.f;
    #pragma unroll 8
    for (int c = 0; c < IN_F; ++c)
        acc += hrow[c] * W[c * OUT_F + lane];
    Wh[(size_t)i * OUT_F + lane] = acc;
    float v1 = acc * a[lane];
    float v2 = acc * a[OUT_F + lane];
    #pragma unroll
    for (int o = 32; o > 0; o >>= 1) {
        v1 += __shfl_xor(v1, o, 64);
        v2 += __shfl_xor(v2, o, 64);
    }
    if (lane == 0) { Wh1[i] = v1; Wh2[i] = v2; }
}

// ---------------- k0T: WhT[f][j] = (bf16)Wh[j][f]   (for MFMA B-fragments)
__global__ __launch_bounds__(256) void k0_transpose(const float* __restrict__ Wh,
                                                    bf16* __restrict__ WhT) {
    __shared__ float lds[OUT_F * 65];
    int tid = threadIdx.x;
    int i0 = blockIdx.x * 64;
    int f = tid & 63;
    int r0 = tid >> 6;
    #pragma unroll
    for (int s = 0; s < 16; ++s) {
        int r = r0 * 16 + s;
        lds[f * 65 + r] = Wh[(size_t)(i0 + r) * OUT_F + f];
    }
    __syncthreads();
    int f2 = tid >> 2;
    int c0 = (tid & 3) * 16;
    #pragma unroll
    for (int s = 0; s < 16; ++s) {
        int c = c0 + s;
        WhT[(size_t)f2 * NN + i0 + c] = (bf16)lds[f2 * 65 + c];
    }
}

// ---------------- k1 (per channel): the ONLY edge reader.
// p[i][j] = bf16( edge>0 ? exp(leaky(Wh1[i]+Wh2[j])*edge) : 0 )   (staged, L3-hot)
// partial[ic][j] = sum over the chunk's rows of float(p)           (no atomics)
// grid (IC1=256 chunks of 16 rows, 2 jhalf) x 256; depth-4 row prefetch.
__global__ __launch_bounds__(256) void k1_colsum(const float* __restrict__ edge_ch,
                                                 const float* __restrict__ Wh1,
                                                 const float* __restrict__ Wh2,
                                                 bf16* __restrict__ p_ch,
                                                 float* __restrict__ partial) {
    int tid = threadIdx.x;
    int j0 = blockIdx.y * 2048 + tid * 8;
    int ic = blockIdx.x;
    int ibase = ic * ROWS1;
    float w2[8];
    {
        f32x4 t0 = *(const f32x4*)&Wh2[j0];
        f32x4 t1 = *(const f32x4*)&Wh2[j0 + 4];
        #pragma unroll
        for (int c = 0; c < 4; ++c) { w2[c] = t0[c]; w2[c + 4] = t1[c]; }
    }
    float s[8] = {0.f, 0.f, 0.f, 0.f, 0.f, 0.f, 0.f, 0.f};
    const float* base = edge_ch + (size_t)ibase * NN + j0;
    bf16* pbase = p_ch + (size_t)ibase * NN + j0;
    // prefetch rows 0..3
    f32x4 r0[4], r1[4];
    #pragma unroll
    for (int t = 0; t < 4; ++t) {
        r0[t] = *(const f32x4*)(base + (size_t)t * NN);
        r1[t] = *(const f32x4*)(base + (size_t)t * NN + 4);
    }
    #pragma unroll 4
    for (int ii = 0; ii < ROWS1; ++ii) {
        int cur = ii & 3;
        f32x4 e0 = r0[cur], e1 = r1[cur];
        int ip = (ii + 4 < ROWS1) ? ii + 4 : ii;   // clamp: harmless reload
        r0[cur] = *(const f32x4*)(base + (size_t)ip * NN);
        r1[cur] = *(const f32x4*)(base + (size_t)ip * NN + 4);
        float wh1 = Wh1[ibase + ii];
        bf16x8 pv;
        #pragma unroll
        for (int c = 0; c < 8; ++c) {
            float ef = c < 4 ? e0[c] : e1[c - 4];
            float xv = wh1 + w2[c];
            float lk = xv > 0.f ? xv : ALPHA * xv;
            float val = ef > 0.f ? __expf(lk * ef) : 0.f;
            bf16 vb = (bf16)val;
            pv[c] = vb;
            s[c] += (float)vb;     // sum the ROUNDED value -> consistent softmax
        }
        *(bf16x8*)(pbase + (size_t)ii * NN) = pv;   // regular store: want L2/L3 residency
    }
    float* pr = partial + (size_t)ic * NN + j0;
    f32x4 o0, o1;
    #pragma unroll
    for (int c = 0; c < 4; ++c) { o0[c] = s[c]; o1[c] = s[c + 4]; }
    *(f32x4*)pr = o0;
    *(f32x4*)(pr + 4) = o1;
}

// ---------------- k1b (per channel): s_col[j] = sum_ic partial[ic][j]
// grid 64 x 256: jl=tid&63, g=tid>>6 sums IC1/4 chunks, LDS combine.
__global__ __launch_bounds__(256) void k1_reduce(const float* __restrict__ partial,
                                                 float* __restrict__ s_col) {
    __shared__ float red[256];
    int tid = threadIdx.x;
    int jl = tid & 63, g = tid >> 6;
    int j = blockIdx.x * 64 + jl;
    float s = 0.f;
    #pragma unroll 8
    for (int t = 0; t < IC1 / 4; ++t)
        s += partial[(size_t)(g * (IC1 / 4) + t) * NN + j];
    red[tid] = s;
    __syncthreads();
    if (tid < 64)
        s_col[j] = red[tid] + red[tid + 64] + red[tid + 128] + red[tid + 192];
}

// ---------------- k2 (per channel): att = p * inv_s (write NT) + hp = att @ Wh (MFMA)
// Reads p bf16 (16 B/lane, L3-hot). Short chain: load -> mul -> store.
// grid (64 itile, 8 jp) x 256; depth-4 step prefetch.
// Wave layout = mfma_f32_16x16x32_bf16 A-fragment (row i = lane&15, k = quad*8+c).
__global__ __launch_bounds__(256) void k2_fused(const bf16* __restrict__ p_ch,
                                                const float* __restrict__ s_col,
                                                const bf16* __restrict__ WhT,
                                                float* __restrict__ att_ch,
                                                float* __restrict__ hp) {
    __shared__ float lds_inv[JCOLS];
    int tid = threadIdx.x;
    int itile = blockIdx.x;
    int jp = blockIdx.y;
    int jbase0 = jp * JCOLS;
    {   // per-block: 1/s for this j-slab into LDS (2 j per thread)
        int t2 = tid * 2;
        float s0 = s_col[jbase0 + t2];
        float s1 = s_col[jbase0 + t2 + 1];
        lds_inv[t2]     = s0 > 0.f ? 1.f / s0 : 0.f;
        lds_inv[t2 + 1] = s1 > 0.f ? 1.f / s1 : 0.f;
    }
    __syncthreads();
    int wave = tid >> 6, lane = tid & 63;
    int n16 = lane & 15, quad = lane >> 4;
    int i_row = itile * 64 + wave * 16 + n16;
    const size_t ebase = (size_t)i_row * NN + jbase0 + quad * 8;
    const bf16* pptr = p_ch + ebase;
    float* aptr = att_ch + ebase;
    const bf16* wbase = WhT + (size_t)n16 * NN + jbase0 + quad * 8;
    f32x4 acc[4] = {};
    // prefetch steps 0..3 (step s covers local j = s*32 + quad*8 .. +7; 16 B/lane)
    bf16x8 pf[4];
    #pragma unroll
    for (int t = 0; t < 4; ++t)
        pf[t] = *(const bf16x8*)(pptr + t * 32);
    #pragma unroll 4
    for (int s = 0; s < JCOLS / 32; ++s) {
        int cur = s & 3;
        bf16x8 pv = pf[cur];
        int sp = (s + 4 < JCOLS / 32) ? s + 4 : s;   // clamp: harmless reload
        pf[cur] = *(const bf16x8*)(pptr + sp * 32);
        int jl = s * 32 + quad * 8;
        f32x4 iv0 = *(const f32x4*)&lds_inv[jl];
        f32x4 iv1 = *(const f32x4*)&lds_inv[jl + 4];
        bf16x8 afrag;
        f32x4 av0, av1;
        #pragma unroll
        for (int c = 0; c < 8; ++c) {
            float isc = c < 4 ? iv0[c] : iv1[c - 4];
            float attv = (float)pv[c] * isc;
            afrag[c] = (bf16)attv;
            if (c < 4) av0[c] = attv; else av1[c - 4] = attv;
        }
        __builtin_nontemporal_store(av0, (f32x4*)(aptr + s * 32));
        __builtin_nontemporal_store(av1, (f32x4*)(aptr + s * 32 + 4));
        #pragma unroll
        for (int ft = 0; ft < 4; ++ft) {
            bf16x8 bfrag = *(const bf16x8*)(wbase + (size_t)ft * 16 * NN + s * 32);
            acc[ft] = __builtin_amdgcn_mfma_f32_16x16x32_bf16(afrag, bfrag, acc[ft], 0, 0, 0);
        }
    }
    // C/D layout: col = lane&15, row = (lane>>4)*4 + reg
    #pragma unroll
    for (int ft = 0; ft < 4; ++ft) {
        #pragma unroll
        for (int r = 0; r < 4; ++r) {
            int row_l = quad * 4 + r;
            int i_g = itile * 64 + wave * 16 + row_l;
            size_t idx = ((size_t)jp * NN + i_g) * OUT_F + ft * 16 + n16;
            hp[idx] = acc[ft][r];
        }
    }
}

// ---------------- k3 (per channel): out[i][ch*64+f] = elu(sum_jp hp)
__global__ __launch_bounds__(256) void k3_combine(const float* __restrict__ hp,
                                                  float* __restrict__ out,
                                                  int kch) {
    int g = blockIdx.x * 256 + threadIdx.x;
    int i = g >> 6;
    int f = g & 63;
    float s = 0.f;
    #pragma unroll
    for (int z = 0; z < JP; ++z)
        s += hp[((size_t)z * NN + i) * OUT_F + f];
    out[(size_t)i * (K_CH * OUT_F) + kch * OUT_F + f] = s > 0.f ? s : __expf(s) - 1.f;
}

extern "C" void kernel_launch(void* const* d_in, const int* in_sizes, int n_in,
                              void* d_out, int out_size, void* d_ws, size_t ws_size,
                              hipStream_t stream) {
    (void)out_size; (void)ws_size;
    const float *h = nullptr, *edge = nullptr, *W = nullptr, *a = nullptr;
    for (int i = 0; i < n_in; ++i) {
        int sz = in_sizes[i];
        if (sz == NN * IN_F)               h    = (const float*)d_in[i];
        else if (sz == K_CH * NN * NN)     edge = (const float*)d_in[i];
        else if (sz == IN_F * OUT_F)       W    = (const float*)d_in[i];
        else if (sz == 2 * OUT_F)          a    = (const float*)d_in[i];
    }

    char* ws = (char*)d_ws;
    size_t off = 0;
    float* Wh      = (float*)(ws + off); off += (size_t)NN * OUT_F * 4;        // 1 MB
    float* Wh1     = (float*)(ws + off); off += NN * 4;                        // 16 KB
    float* Wh2     = (float*)(ws + off); off += NN * 4;                        // 16 KB
    float* s_col   = (float*)(ws + off); off += NN * 4;                        // 16 KB
    bf16*  WhT     = (bf16*) (ws + off); off += (size_t)OUT_F * NN * 2;        // 512 KB
    float* partial = (float*)(ws + off); off += (size_t)IC1 * NN * 4;         // 4 MB
    float* hp      = (float*)(ws + off); off += (size_t)JP * NN * OUT_F * 4;  // 8.4 MB
    bf16*  p_buf   = (bf16*) (ws + off); off += (size_t)NN * NN * 2;          // 33.6 MB

    float* out_h   = (float*)d_out;
    float* att_out = out_h + (size_t)NN * (K_CH * OUT_F);

    k0_wh<<<dim3(NN / 4), 256, 0, stream>>>(h, W, a, Wh, Wh1, Wh2);
    k0_transpose<<<dim3(NN / 64), 256, 0, stream>>>(Wh, WhT);

    // Per-channel pipeline: k1 reads edge ONCE, stages bf16 p (L3-hot for k2).
    for (int ch = 0; ch < K_CH; ++ch) {
        const float* edge_ch = edge + (size_t)ch * NN * NN;
        float* att_ch = att_out + (size_t)ch * NN * NN;
        k1_colsum<<<dim3(IC1, 2), 256, 0, stream>>>(edge_ch, Wh1, Wh2, p_buf, partial);
        k1_reduce<<<dim3(NN / 64), 256, 0, stream>>>(partial, s_col);
        k2_fused<<<dim3(64, JP), 256, 0, stream>>>(p_buf, s_col, WhT, att_ch, hp);
        k3_combine<<<dim3(NN * OUT_F / 256), 256, 0, stream>>>(hp, out_h, ch);
    }
}

// Round 8
// 625.199 us; speedup vs baseline: 1.0311x; 1.0311x over previous
//
#include <hip/hip_runtime.h>

#define NN 4096
#define IN_F 256
#define OUT_F 64
#define K_CH 4
#define ALPHA 0.2f
#define JP 8           // j-partitions per channel in k2
#define JCOLS 512      // NN / JP
#define ROWS1 16       // rows per k1 chunk
#define IC1 256        // NN / ROWS1 chunks per channel

typedef __bf16 bf16;
typedef __attribute__((ext_vector_type(8))) __bf16 bf16x8;
typedef __attribute__((ext_vector_type(4))) float f32x4;

// ---------------- k0: Wh = h@W (fp32) ; Wh1 = Wh@a[:64] ; Wh2 = Wh@a[64:]
__global__ __launch_bounds__(256) void k0_wh(const float* __restrict__ h,
                                             const float* __restrict__ W,
                                             const float* __restrict__ a,
                                             float* __restrict__ Wh,
                                             float* __restrict__ Wh1,
                                             float* __restrict__ Wh2) {
    int tid = threadIdx.x;
    int wave = tid >> 6, lane = tid & 63;
    int i = blockIdx.x * 4 + wave;
    const float* hrow = h + (size_t)i * IN_F;
    float acc = 0.f;
    #pragma unroll 8
    for (int c = 0; c < IN_F; ++c)
        acc += hrow[c] * W[c * OUT_F + lane];
    Wh[(size_t)i * OUT_F + lane] = acc;
    float v1 = acc * a[lane];
    float v2 = acc * a[OUT_F + lane];
    #pragma unroll
    for (int o = 32; o > 0; o >>= 1) {
        v1 += __shfl_xor(v1, o, 64);
        v2 += __shfl_xor(v2, o, 64);
    }
    if (lane == 0) { Wh1[i] = v1; Wh2[i] = v2; }
}

// ---------------- k0T: WhT[f][j] = (bf16)Wh[j][f]   (for MFMA B-fragments)
__global__ __launch_bounds__(256) void k0_transpose(const float* __restrict__ Wh,
                                                    bf16* __restrict__ WhT) {
    __shared__ float lds[OUT_F * 65];
    int tid = threadIdx.x;
    int i0 = blockIdx.x * 64;
    int f = tid & 63;
    int r0 = tid >> 6;
    #pragma unroll
    for (int s = 0; s < 16; ++s) {
        int r = r0 * 16 + s;
        lds[f * 65 + r] = Wh[(size_t)(i0 + r) * OUT_F + f];
    }
    __syncthreads();
    int f2 = tid >> 2;
    int c0 = (tid & 3) * 16;
    #pragma unroll
    for (int s = 0; s < 16; ++s) {
        int c = c0 + s;
        WhT[(size_t)f2 * NN + i0 + c] = (bf16)lds[f2 * 65 + c];
    }
}

// ---------------- k1 (full-K): the ONLY edge reader.
// p[k][i][j] = bf16( edge>0 ? exp(leaky(Wh1[i]+Wh2[j])*edge) : 0 )  (L3-resident)
// partial[k][ic][j] = chunk column sums (no atomics)
// grid (IC1=256, 2 jhalf, 4 k) x 256 = 2048 blocks; depth-4 row prefetch.
__global__ __launch_bounds__(256) void k1_colsum(const float* __restrict__ edge,
                                                 const float* __restrict__ Wh1,
                                                 const float* __restrict__ Wh2,
                                                 bf16* __restrict__ p_buf,
                                                 float* __restrict__ partial) {
    int tid = threadIdx.x;
    int kch = blockIdx.z;
    int j0 = blockIdx.y * 2048 + tid * 8;
    int ic = blockIdx.x;
    int ibase = ic * ROWS1;
    float w2[8];
    {
        f32x4 t0 = *(const f32x4*)&Wh2[j0];
        f32x4 t1 = *(const f32x4*)&Wh2[j0 + 4];
        #pragma unroll
        for (int c = 0; c < 4; ++c) { w2[c] = t0[c]; w2[c + 4] = t1[c]; }
    }
    float s[8] = {0.f, 0.f, 0.f, 0.f, 0.f, 0.f, 0.f, 0.f};
    const float* base = edge + ((size_t)kch * NN + ibase) * NN + j0;
    bf16* pbase = p_buf + ((size_t)kch * NN + ibase) * NN + j0;
    f32x4 r0[4], r1[4];
    #pragma unroll
    for (int t = 0; t < 4; ++t) {
        r0[t] = *(const f32x4*)(base + (size_t)t * NN);
        r1[t] = *(const f32x4*)(base + (size_t)t * NN + 4);
    }
    #pragma unroll 4
    for (int ii = 0; ii < ROWS1; ++ii) {
        int cur = ii & 3;
        f32x4 e0 = r0[cur], e1 = r1[cur];
        int ip = (ii + 4 < ROWS1) ? ii + 4 : ii;   // clamp: harmless reload
        r0[cur] = *(const f32x4*)(base + (size_t)ip * NN);
        r1[cur] = *(const f32x4*)(base + (size_t)ip * NN + 4);
        float wh1 = Wh1[ibase + ii];
        bf16x8 pv;
        #pragma unroll
        for (int c = 0; c < 8; ++c) {
            float ef = c < 4 ? e0[c] : e1[c - 4];
            float xv = wh1 + w2[c];
            float lk = xv > 0.f ? xv : ALPHA * xv;
            float val = ef > 0.f ? __expf(lk * ef) : 0.f;
            bf16 vb = (bf16)val;
            pv[c] = vb;
            s[c] += (float)vb;     // sum the ROUNDED value -> consistent softmax
        }
        *(bf16x8*)(pbase + (size_t)ii * NN) = pv;  // regular store: want L3 residency
    }
    float* pr = partial + ((size_t)kch * IC1 + ic) * NN + j0;
    f32x4 o0, o1;
    #pragma unroll
    for (int c = 0; c < 4; ++c) { o0[c] = s[c]; o1[c] = s[c + 4]; }
    *(f32x4*)pr = o0;
    *(f32x4*)(pr + 4) = o1;
}

// ---------------- k1b (full-K): s_inv[k][j] = 1 / sum_ic partial[k][ic][j]
// grid (64, 4) x 256: jl=tid&63, g=tid>>6 sums IC1/4 chunks, LDS combine.
__global__ __launch_bounds__(256) void k1_reduce(const float* __restrict__ partial,
                                                 float* __restrict__ s_inv) {
    __shared__ float red[256];
    int tid = threadIdx.x;
    int kch = blockIdx.y;
    int jl = tid & 63, g = tid >> 6;
    int j = blockIdx.x * 64 + jl;
    const float* pb = partial + (size_t)kch * IC1 * NN;
    float s = 0.f;
    #pragma unroll 8
    for (int t = 0; t < IC1 / 4; ++t)
        s += pb[(size_t)(g * (IC1 / 4) + t) * NN + j];
    red[tid] = s;
    __syncthreads();
    if (tid < 64) {
        float tot = red[tid] + red[tid + 64] + red[tid + 128] + red[tid + 192];
        s_inv[kch * NN + j] = tot > 0.f ? 1.f / tot : 0.f;
    }
}

// ---------------- k2 (full-K): att = p * inv_s (NT write) + hp = att @ Wh (MFMA)
// Reads p bf16 (16 B/lane, largely L3-hot). Chain: load -> mul -> store.
// grid (64 itile, 32 z=kch*8+jp) x 256; depth-4 step prefetch.
// Wave layout = mfma_f32_16x16x32_bf16 A-fragment (row i = lane&15, k = quad*8+c).
__global__ __launch_bounds__(256) void k2_fused(const bf16* __restrict__ p_buf,
                                                const float* __restrict__ s_inv,
                                                const bf16* __restrict__ WhT,
                                                float* __restrict__ att_out,
                                                float* __restrict__ hp) {
    __shared__ float lds_inv[JCOLS];
    int tid = threadIdx.x;
    int itile = blockIdx.x;
    int z = blockIdx.y;
    int kch = z >> 3, jp = z & 7;
    int jbase0 = jp * JCOLS;
    {   // per-block: inv_s for this j-slab into LDS (2 j per thread)
        int t2 = tid * 2;
        lds_inv[t2]     = s_inv[kch * NN + jbase0 + t2];
        lds_inv[t2 + 1] = s_inv[kch * NN + jbase0 + t2 + 1];
    }
    __syncthreads();
    int wave = tid >> 6, lane = tid & 63;
    int n16 = lane & 15, quad = lane >> 4;
    int i_row = itile * 64 + wave * 16 + n16;
    const size_t ebase = ((size_t)kch * NN + i_row) * NN + jbase0 + quad * 8;
    const bf16* pptr = p_buf + ebase;
    float* aptr = att_out + ebase;
    const bf16* wbase = WhT + (size_t)n16 * NN + jbase0 + quad * 8;
    f32x4 acc[4] = {};
    bf16x8 pf[4];
    #pragma unroll
    for (int t = 0; t < 4; ++t)
        pf[t] = *(const bf16x8*)(pptr + t * 32);
    #pragma unroll 4
    for (int s = 0; s < JCOLS / 32; ++s) {
        int cur = s & 3;
        bf16x8 pv = pf[cur];
        int sp = (s + 4 < JCOLS / 32) ? s + 4 : s;   // clamp: harmless reload
        pf[cur] = *(const bf16x8*)(pptr + sp * 32);
        int jl = s * 32 + quad * 8;
        f32x4 iv0 = *(const f32x4*)&lds_inv[jl];
        f32x4 iv1 = *(const f32x4*)&lds_inv[jl + 4];
        bf16x8 afrag;
        f32x4 av0, av1;
        #pragma unroll
        for (int c = 0; c < 8; ++c) {
            float isc = c < 4 ? iv0[c] : iv1[c - 4];
            float attv = (float)pv[c] * isc;
            afrag[c] = (bf16)attv;
            if (c < 4) av0[c] = attv; else av1[c - 4] = attv;
        }
        __builtin_nontemporal_store(av0, (f32x4*)(aptr + s * 32));
        __builtin_nontemporal_store(av1, (f32x4*)(aptr + s * 32 + 4));
        #pragma unroll
        for (int ft = 0; ft < 4; ++ft) {
            bf16x8 bfrag = *(const bf16x8*)(wbase + (size_t)ft * 16 * NN + s * 32);
            acc[ft] = __builtin_amdgcn_mfma_f32_16x16x32_bf16(afrag, bfrag, acc[ft], 0, 0, 0);
        }
    }
    // C/D layout: col = lane&15, row = (lane>>4)*4 + reg
    #pragma unroll
    for (int ft = 0; ft < 4; ++ft) {
        #pragma unroll
        for (int r = 0; r < 4; ++r) {
            int row_l = quad * 4 + r;
            int i_g = itile * 64 + wave * 16 + row_l;
            size_t idx = ((size_t)z * NN + i_g) * OUT_F + ft * 16 + n16;
            hp[idx] = acc[ft][r];
        }
    }
}

// ---------------- k3 (full-K): out[i][k*64+f] = elu(sum_jp hp[k*8+jp])
__global__ __launch_bounds__(256) void k3_combine(const float* __restrict__ hp,
                                                  float* __restrict__ out) {
    int g = blockIdx.x * 256 + threadIdx.x;
    int i = g >> 8;
    int rem = g & 255;
    int kch = rem >> 6;
    int f = rem & 63;
    float s = 0.f;
    #pragma unroll
    for (int z = 0; z < JP; ++z)
        s += hp[(((size_t)(kch * JP + z)) * NN + i) * OUT_F + f];
    out[g] = s > 0.f ? s : __expf(s) - 1.f;
}

extern "C" void kernel_launch(void* const* d_in, const int* in_sizes, int n_in,
                              void* d_out, int out_size, void* d_ws, size_t ws_size,
                              hipStream_t stream) {
    (void)out_size; (void)ws_size;
    const float *h = nullptr, *edge = nullptr, *W = nullptr, *a = nullptr;
    for (int i = 0; i < n_in; ++i) {
        int sz = in_sizes[i];
        if (sz == NN * IN_F)               h    = (const float*)d_in[i];
        else if (sz == K_CH * NN * NN)     edge = (const float*)d_in[i];
        else if (sz == IN_F * OUT_F)       W    = (const float*)d_in[i];
        else if (sz == 2 * OUT_F)          a    = (const float*)d_in[i];
    }

    char* ws = (char*)d_ws;
    size_t off = 0;
    float* Wh      = (float*)(ws + off); off += (size_t)NN * OUT_F * 4;              // 1 MB
    float* Wh1     = (float*)(ws + off); off += NN * 4;                              // 16 KB
    float* Wh2     = (float*)(ws + off); off += NN * 4;                              // 16 KB
    float* s_inv   = (float*)(ws + off); off += (size_t)K_CH * NN * 4;               // 64 KB
    bf16*  WhT     = (bf16*) (ws + off); off += (size_t)OUT_F * NN * 2;              // 512 KB
    float* partial = (float*)(ws + off); off += (size_t)K_CH * IC1 * NN * 4;         // 16.8 MB
    float* hp      = (float*)(ws + off); off += (size_t)K_CH * JP * NN * OUT_F * 4;  // 33.6 MB
    bf16*  p_buf   = (bf16*) (ws + off); off += (size_t)K_CH * NN * NN * 2;          // 134 MB

    float* out_h   = (float*)d_out;
    float* att_out = out_h + (size_t)NN * (K_CH * OUT_F);

    k0_wh<<<dim3(NN / 4), 256, 0, stream>>>(h, W, a, Wh, Wh1, Wh2);
    k0_transpose<<<dim3(NN / 64), 256, 0, stream>>>(Wh, WhT);
    k1_colsum<<<dim3(IC1, 2, K_CH), 256, 0, stream>>>(edge, Wh1, Wh2, p_buf, partial);
    k1_reduce<<<dim3(NN / 64, K_CH), 256, 0, stream>>>(partial, s_inv);
    k2_fused<<<dim3(64, K_CH * JP), 256, 0, stream>>>(p_buf, s_inv, WhT, att_out, hp);
    k3_combine<<<dim3((NN * K_CH * OUT_F) / 256), 256, 0, stream>>>(hp, out_h);
}

// Round 9
// 593.899 us; speedup vs baseline: 1.0854x; 1.0527x over previous
//
#include <hip/hip_runtime.h>

#define NN 4096
#define IN_F 256
#define OUT_F 64
#define K_CH 4
#define ALPHA 0.2f
#define JP 16          // j-partitions per channel in k2
#define JCOLS 256      // NN / JP
#define ROWS1 32       // rows per k1 chunk
#define IC1 128        // NN / ROWS1 chunks per channel
#define BSTRIDE 264    // LDS B-slab row stride (bf16 elems): even 8/bank, 16B-aligned

typedef __bf16 bf16;
typedef __attribute__((ext_vector_type(8))) __bf16 bf16x8;
typedef __attribute__((ext_vector_type(4))) __bf16 bf16x4;
typedef __attribute__((ext_vector_type(4))) float f32x4;

// ---------------- k0: Wh = h@W (fp32) ; Wh1 = Wh@a[:64] ; Wh2 = Wh@a[64:]
__global__ __launch_bounds__(256) void k0_wh(const float* __restrict__ h,
                                             const float* __restrict__ W,
                                             const float* __restrict__ a,
                                             float* __restrict__ Wh,
                                             float* __restrict__ Wh1,
                                             float* __restrict__ Wh2) {
    int tid = threadIdx.x;
    int wave = tid >> 6, lane = tid & 63;
    int i = blockIdx.x * 4 + wave;
    const float* hrow = h + (size_t)i * IN_F;
    float acc = 0.f;
    #pragma unroll 8
    for (int c = 0; c < IN_F; ++c)
        acc += hrow[c] * W[c * OUT_F + lane];
    Wh[(size_t)i * OUT_F + lane] = acc;
    float v1 = acc * a[lane];
    float v2 = acc * a[OUT_F + lane];
    #pragma unroll
    for (int o = 32; o > 0; o >>= 1) {
        v1 += __shfl_xor(v1, o, 64);
        v2 += __shfl_xor(v2, o, 64);
    }
    if (lane == 0) { Wh1[i] = v1; Wh2[i] = v2; }
}

// ---------------- k0T: WhT[f][j] = (bf16)Wh[j][f]   (for MFMA B-fragments)
__global__ __launch_bounds__(256) void k0_transpose(const float* __restrict__ Wh,
                                                    bf16* __restrict__ WhT) {
    __shared__ float lds[OUT_F * 65];
    int tid = threadIdx.x;
    int i0 = blockIdx.x * 64;
    int f = tid & 63;
    int r0 = tid >> 6;
    #pragma unroll
    for (int s = 0; s < 16; ++s) {
        int r = r0 * 16 + s;
        lds[f * 65 + r] = Wh[(size_t)(i0 + r) * OUT_F + f];
    }
    __syncthreads();
    int f2 = tid >> 2;
    int c0 = (tid & 3) * 16;
    #pragma unroll
    for (int s = 0; s < 16; ++s) {
        int c = c0 + s;
        WhT[(size_t)f2 * NN + i0 + c] = (bf16)lds[f2 * 65 + c];
    }
}

// ---------------- k1: the ONLY edge reader. 4 j per lane -> fully contiguous
// 16B loads. p[k][i][j] = bf16(masked exp); partial[k][ic][j] = chunk col sums.
// grid (IC1=128 chunks of 32 rows, 4 jquarter, 4 k) x 256; depth-8 row prefetch.
__global__ __launch_bounds__(256) void k1_colsum(const float* __restrict__ edge,
                                                 const float* __restrict__ Wh1,
                                                 const float* __restrict__ Wh2,
                                                 bf16* __restrict__ p_buf,
                                                 float* __restrict__ partial) {
    int tid = threadIdx.x;
    int kch = blockIdx.z;
    int j0 = blockIdx.y * 1024 + tid * 4;
    int ic = blockIdx.x;
    int ibase = ic * ROWS1;
    f32x4 w2 = *(const f32x4*)&Wh2[j0];
    f32x4 s = {0.f, 0.f, 0.f, 0.f};
    const float* base = edge + ((size_t)kch * NN + ibase) * NN + j0;
    bf16* pbase = p_buf + ((size_t)kch * NN + ibase) * NN + j0;
    f32x4 r[8];
    #pragma unroll
    for (int t = 0; t < 8; ++t)
        r[t] = *(const f32x4*)(base + (size_t)t * NN);
    #pragma unroll
    for (int ii = 0; ii < ROWS1; ++ii) {
        int cur = ii & 7;
        f32x4 e = r[cur];
        int ip = (ii + 8 < ROWS1) ? ii + 8 : ii;   // clamp: harmless reload
        r[cur] = *(const f32x4*)(base + (size_t)ip * NN);
        float wh1 = Wh1[ibase + ii];
        bf16x4 pv;
        #pragma unroll
        for (int c = 0; c < 4; ++c) {
            float xv = wh1 + w2[c];
            float lk = xv > 0.f ? xv : ALPHA * xv;
            float val = e[c] > 0.f ? __expf(lk * e[c]) : 0.f;
            bf16 vb = (bf16)val;
            pv[c] = vb;
            s[c] += (float)vb;     // sum the ROUNDED value -> consistent softmax
        }
        *(bf16x4*)(pbase + (size_t)ii * NN) = pv;
    }
    *(f32x4*)(partial + ((size_t)kch * IC1 + ic) * NN + j0) = s;
}

// ---------------- k1b: s_inv[k][j] = 1 / sum_ic partial[k][ic][j]
__global__ __launch_bounds__(256) void k1_reduce(const float* __restrict__ partial,
                                                 float* __restrict__ s_inv) {
    __shared__ float red[256];
    int tid = threadIdx.x;
    int kch = blockIdx.y;
    int jl = tid & 63, g = tid >> 6;
    int j = blockIdx.x * 64 + jl;
    const float* pb = partial + (size_t)kch * IC1 * NN;
    float s = 0.f;
    #pragma unroll 8
    for (int t = 0; t < IC1 / 4; ++t)
        s += pb[(size_t)(g * (IC1 / 4) + t) * NN + j];
    red[tid] = s;
    __syncthreads();
    if (tid < 64) {
        float tot = red[tid] + red[tid + 64] + red[tid + 128] + red[tid + 192];
        s_inv[kch * NN + j] = tot > 0.f ? 1.f / tot : 0.f;
    }
}

// ---------------- k2: att = p * inv_s + hp = att @ Wh (MFMA).
// B-fragments staged in LDS (ds_read, lgkmcnt) so the vmcnt queue carries ONLY
// the deep p-load / att-store stream. grid (64 itile, 64 z=kch*16+jp) x 256.
// Wave layout = mfma_f32_16x16x32_bf16 A-fragment (row i = lane&15, k = quad*8+c).
__global__ __launch_bounds__(256) void k2_fused(const bf16* __restrict__ p_buf,
                                                const float* __restrict__ s_inv,
                                                const bf16* __restrict__ WhT,
                                                float* __restrict__ att_out,
                                                float* __restrict__ hp) {
    __shared__ bf16 ldsB[OUT_F * BSTRIDE];
    __shared__ float lds_inv[JCOLS];
    int tid = threadIdx.x;
    int itile = blockIdx.x;
    int z = blockIdx.y;
    int kch = z >> 4, jp = z & 15;
    int jbase0 = jp * JCOLS;
    {   // stage the 64 x 256 WhT slab into LDS (one-time, L2-hot source)
        int f = tid >> 2, part = (tid & 3) * 64;
        #pragma unroll
        for (int u = 0; u < 8; ++u) {
            bf16x8 v = *(const bf16x8*)(WhT + (size_t)f * NN + jbase0 + part + u * 8);
            *(bf16x8*)&ldsB[f * BSTRIDE + part + u * 8] = v;
        }
        lds_inv[tid] = s_inv[kch * NN + jbase0 + tid];
    }
    __syncthreads();
    int wave = tid >> 6, lane = tid & 63;
    int n16 = lane & 15, quad = lane >> 4;
    int i_row = itile * 64 + wave * 16 + n16;
    const size_t ebase = ((size_t)kch * NN + i_row) * NN + jbase0 + quad * 8;
    const bf16* pptr = p_buf + ebase;
    float* aptr = att_out + ebase;
    f32x4 acc[4] = {};
    bf16x8 pf[4];
    #pragma unroll
    for (int t = 0; t < 4; ++t)
        pf[t] = *(const bf16x8*)(pptr + t * 32);
    #pragma unroll
    for (int s = 0; s < JCOLS / 32; ++s) {
        int cur = s & 3;
        bf16x8 pv = pf[cur];
        int sp = (s + 4 < JCOLS / 32) ? s + 4 : s;   // clamp: harmless reload
        pf[cur] = *(const bf16x8*)(pptr + sp * 32);
        int jl = s * 32 + quad * 8;
        f32x4 iv0 = *(const f32x4*)&lds_inv[jl];
        f32x4 iv1 = *(const f32x4*)&lds_inv[jl + 4];
        bf16x8 afrag;
        f32x4 av0, av1;
        #pragma unroll
        for (int c = 0; c < 8; ++c) {
            float isc = c < 4 ? iv0[c] : iv1[c - 4];
            float attv = (float)pv[c] * isc;
            afrag[c] = (bf16)attv;
            if (c < 4) av0[c] = attv; else av1[c - 4] = attv;
        }
        *(f32x4*)(aptr + s * 32) = av0;        // plain stores: L2 merges halves
        *(f32x4*)(aptr + s * 32 + 4) = av1;
        #pragma unroll
        for (int ft = 0; ft < 4; ++ft) {
            bf16x8 bfrag = *(const bf16x8*)&ldsB[(ft * 16 + n16) * BSTRIDE + jl];
            acc[ft] = __builtin_amdgcn_mfma_f32_16x16x32_bf16(afrag, bfrag, acc[ft], 0, 0, 0);
        }
    }
    // C/D layout: col = lane&15, row = (lane>>4)*4 + reg
    #pragma unroll
    for (int ft = 0; ft < 4; ++ft) {
        #pragma unroll
        for (int r = 0; r < 4; ++r) {
            int row_l = quad * 4 + r;
            int i_g = itile * 64 + wave * 16 + row_l;
            size_t idx = ((size_t)z * NN + i_g) * OUT_F + ft * 16 + n16;
            hp[idx] = acc[ft][r];
        }
    }
}

// ---------------- k3: out[i][k*64+f] = elu(sum_jp hp[k*16+jp])
__global__ __launch_bounds__(256) void k3_combine(const float* __restrict__ hp,
                                                  float* __restrict__ out) {
    int g = blockIdx.x * 256 + threadIdx.x;
    int i = g >> 8;
    int rem = g & 255;
    int kch = rem >> 6;
    int f = rem & 63;
    float s = 0.f;
    #pragma unroll
    for (int z = 0; z < JP; ++z)
        s += hp[(((size_t)(kch * JP + z)) * NN + i) * OUT_F + f];
    out[g] = s > 0.f ? s : __expf(s) - 1.f;
}

extern "C" void kernel_launch(void* const* d_in, const int* in_sizes, int n_in,
                              void* d_out, int out_size, void* d_ws, size_t ws_size,
                              hipStream_t stream) {
    (void)out_size; (void)ws_size;
    const float *h = nullptr, *edge = nullptr, *W = nullptr, *a = nullptr;
    for (int i = 0; i < n_in; ++i) {
        int sz = in_sizes[i];
        if (sz == NN * IN_F)               h    = (const float*)d_in[i];
        else if (sz == K_CH * NN * NN)     edge = (const float*)d_in[i];
        else if (sz == IN_F * OUT_F)       W    = (const float*)d_in[i];
        else if (sz == 2 * OUT_F)          a    = (const float*)d_in[i];
    }

    char* ws = (char*)d_ws;
    size_t off = 0;
    float* Wh      = (float*)(ws + off); off += (size_t)NN * OUT_F * 4;               // 1 MB
    float* Wh1     = (float*)(ws + off); off += NN * 4;                               // 16 KB
    float* Wh2     = (float*)(ws + off); off += NN * 4;                               // 16 KB
    float* s_inv   = (float*)(ws + off); off += (size_t)K_CH * NN * 4;                // 64 KB
    bf16*  WhT     = (bf16*) (ws + off); off += (size_t)OUT_F * NN * 2;               // 512 KB
    float* partial = (float*)(ws + off); off += (size_t)K_CH * IC1 * NN * 4;          // 8.4 MB
    float* hp      = (float*)(ws + off); off += (size_t)K_CH * JP * NN * OUT_F * 4;   // 67 MB
    bf16*  p_buf   = (bf16*) (ws + off); off += (size_t)K_CH * NN * NN * 2;           // 134 MB

    float* out_h   = (float*)d_out;
    float* att_out = out_h + (size_t)NN * (K_CH * OUT_F);

    k0_wh<<<dim3(NN / 4), 256, 0, stream>>>(h, W, a, Wh, Wh1, Wh2);
    k0_transpose<<<dim3(NN / 64), 256, 0, stream>>>(Wh, WhT);
    k1_colsum<<<dim3(IC1, 4, K_CH), 256, 0, stream>>>(edge, Wh1, Wh2, p_buf, partial);
    k1_reduce<<<dim3(NN / 64, K_CH), 256, 0, stream>>>(partial, s_inv);
    k2_fused<<<dim3(64, K_CH * JP), 256, 0, stream>>>(p_buf, s_inv, WhT, att_out, hp);
    k3_combine<<<dim3((NN * K_CH * OUT_F) / 256), 256, 0, stream>>>(hp, out_h);
}

// Round 10
// 591.270 us; speedup vs baseline: 1.0903x; 1.0044x over previous
//
#include <hip/hip_runtime.h>

#define NN 4096
#define IN_F 256
#define OUT_F 64
#define K_CH 4
#define ALPHA 0.2f
#define ROWS1 32       // rows per k1 chunk
#define IC1 128        // NN / ROWS1 chunks per channel
#define BSTRIDE 264    // LDS B-slab row stride (bf16 elems): even 8/bank, 16B-aligned

typedef __bf16 bf16;
typedef __attribute__((ext_vector_type(8))) __bf16 bf16x8;
typedef __attribute__((ext_vector_type(4))) __bf16 bf16x4;
typedef __attribute__((ext_vector_type(4))) float f32x4;

// ---------------- k0: Wh = h@W (fp32) ; Wh1 = Wh@a[:64] ; Wh2 = Wh@a[64:]
__global__ __launch_bounds__(256) void k0_wh(const float* __restrict__ h,
                                             const float* __restrict__ W,
                                             const float* __restrict__ a,
                                             float* __restrict__ Wh,
                                             float* __restrict__ Wh1,
                                             float* __restrict__ Wh2) {
    int tid = threadIdx.x;
    int wave = tid >> 6, lane = tid & 63;
    int i = blockIdx.x * 4 + wave;
    const float* hrow = h + (size_t)i * IN_F;
    float acc = 0.f;
    #pragma unroll 8
    for (int c = 0; c < IN_F; ++c)
        acc += hrow[c] * W[c * OUT_F + lane];
    Wh[(size_t)i * OUT_F + lane] = acc;
    float v1 = acc * a[lane];
    float v2 = acc * a[OUT_F + lane];
    #pragma unroll
    for (int o = 32; o > 0; o >>= 1) {
        v1 += __shfl_xor(v1, o, 64);
        v2 += __shfl_xor(v2, o, 64);
    }
    if (lane == 0) { Wh1[i] = v1; Wh2[i] = v2; }
}

// ---------------- k0T: WhT[f][j] = (bf16)Wh[j][f]   (for MFMA B-fragments)
__global__ __launch_bounds__(256) void k0_transpose(const float* __restrict__ Wh,
                                                    bf16* __restrict__ WhT) {
    __shared__ float lds[OUT_F * 65];
    int tid = threadIdx.x;
    int i0 = blockIdx.x * 64;
    int f = tid & 63;
    int r0 = tid >> 6;
    #pragma unroll
    for (int s = 0; s < 16; ++s) {
        int r = r0 * 16 + s;
        lds[f * 65 + r] = Wh[(size_t)(i0 + r) * OUT_F + f];
    }
    __syncthreads();
    int f2 = tid >> 2;
    int c0 = (tid & 3) * 16;
    #pragma unroll
    for (int s = 0; s < 16; ++s) {
        int c = c0 + s;
        WhT[(size_t)f2 * NN + i0 + c] = (bf16)lds[f2 * 65 + c];
    }
}

// ---------------- k1: the ONLY edge reader. 4 j per lane -> fully contiguous
// 16B loads. p[k][i][j] = bf16(masked exp); partial[k][ic][j] = chunk col sums.
// grid (IC1=128 chunks of 32 rows, 4 jquarter, 4 k) x 256; depth-8 row prefetch.
__global__ __launch_bounds__(256) void k1_colsum(const float* __restrict__ edge,
                                                 const float* __restrict__ Wh1,
                                                 const float* __restrict__ Wh2,
                                                 bf16* __restrict__ p_buf,
                                                 float* __restrict__ partial) {
    int tid = threadIdx.x;
    int kch = blockIdx.z;
    int j0 = blockIdx.y * 1024 + tid * 4;
    int ic = blockIdx.x;
    int ibase = ic * ROWS1;
    f32x4 w2 = *(const f32x4*)&Wh2[j0];
    f32x4 s = {0.f, 0.f, 0.f, 0.f};
    const float* base = edge + ((size_t)kch * NN + ibase) * NN + j0;
    bf16* pbase = p_buf + ((size_t)kch * NN + ibase) * NN + j0;
    f32x4 r[8];
    #pragma unroll
    for (int t = 0; t < 8; ++t)
        r[t] = *(const f32x4*)(base + (size_t)t * NN);
    #pragma unroll
    for (int ii = 0; ii < ROWS1; ++ii) {
        int cur = ii & 7;
        f32x4 e = r[cur];
        int ip = (ii + 8 < ROWS1) ? ii + 8 : ii;   // clamp: harmless reload
        r[cur] = *(const f32x4*)(base + (size_t)ip * NN);
        float wh1 = Wh1[ibase + ii];
        bf16x4 pv;
        #pragma unroll
        for (int c = 0; c < 4; ++c) {
            float xv = wh1 + w2[c];
            float lk = xv > 0.f ? xv : ALPHA * xv;
            float val = e[c] > 0.f ? __expf(lk * e[c]) : 0.f;
            bf16 vb = (bf16)val;
            pv[c] = vb;
            s[c] += (float)vb;     // sum the ROUNDED value -> consistent softmax
        }
        *(bf16x4*)(pbase + (size_t)ii * NN) = pv;
    }
    *(f32x4*)(partial + ((size_t)kch * IC1 + ic) * NN + j0) = s;
}

// ---------------- k1b: s_inv[k][j] = 1 / sum_ic partial[k][ic][j]
__global__ __launch_bounds__(256) void k1_reduce(const float* __restrict__ partial,
                                                 float* __restrict__ s_inv) {
    __shared__ float red[256];
    int tid = threadIdx.x;
    int kch = blockIdx.y;
    int jl = tid & 63, g = tid >> 6;
    int j = blockIdx.x * 64 + jl;
    const float* pb = partial + (size_t)kch * IC1 * NN;
    float s = 0.f;
    #pragma unroll 8
    for (int t = 0; t < IC1 / 4; ++t)
        s += pb[(size_t)(g * (IC1 / 4) + t) * NN + j];
    red[tid] = s;
    __syncthreads();
    if (tid < 64) {
        float tot = red[tid] + red[tid + 64] + red[tid + 128] + red[tid + 192];
        s_inv[kch * NN + j] = tot > 0.f ? 1.f / tot : 0.f;
    }
}

// ---------------- k2: FULL-j per block. att = p*inv (write) + acc = att @ Wh (MFMA),
// then elu(acc) -> out directly. No hp buffer, no k3.
// grid (64 itile, 4 kch) x 256 (4 waves; wave owns 16 rows, all 4096 j).
// B-slabs (64f x 256j) re-staged in LDS per slab; depth-8 p-prefetch ring runs
// through slab boundaries (p is j-linear).
// Wave layout = mfma_f32_16x16x32_bf16 A-fragment (row i = lane&15, k = quad*8+c).
__global__ __launch_bounds__(256) void k2_fused(const bf16* __restrict__ p_buf,
                                                const float* __restrict__ s_inv,
                                                const bf16* __restrict__ WhT,
                                                float* __restrict__ att_out,
                                                float* __restrict__ out) {
    __shared__ bf16 ldsB[OUT_F * BSTRIDE];
    __shared__ float lds_inv[NN];
    int tid = threadIdx.x;
    int itile = blockIdx.x;
    int kch = blockIdx.y;
    // stage inv_s for ALL j once (16 KB)
    #pragma unroll
    for (int t = 0; t < NN / 256; ++t)
        lds_inv[t * 256 + tid] = s_inv[kch * NN + t * 256 + tid];
    int wave = tid >> 6, lane = tid & 63;
    int n16 = lane & 15, quad = lane >> 4;
    int i_row = itile * 64 + wave * 16 + n16;
    const size_t ebase = ((size_t)kch * NN + i_row) * NN + quad * 8;
    const bf16* pptr = p_buf + ebase;
    float* aptr = att_out + ebase;
    f32x4 acc[4] = {};
    // depth-8 prefetch ring over 128 global steps (32 j per step)
    bf16x8 pf[8];
    #pragma unroll
    for (int t = 0; t < 8; ++t)
        pf[t] = *(const bf16x8*)(pptr + t * 32);
    int f = tid >> 2, part = (tid & 3) * 64;
    const bf16* wsrc = WhT + (size_t)f * NN + part;
    for (int slab = 0; slab < 16; ++slab) {
        __syncthreads();   // protect ldsB from previous slab's readers
        #pragma unroll
        for (int u = 0; u < 8; ++u) {
            bf16x8 v = *(const bf16x8*)(wsrc + slab * 256 + u * 8);
            *(bf16x8*)&ldsB[f * BSTRIDE + part + u * 8] = v;
        }
        __syncthreads();
        #pragma unroll
        for (int t = 0; t < 8; ++t) {
            int g = slab * 8 + t;
            int cur = g & 7;
            bf16x8 pv = pf[cur];
            int gp = (g + 8 < 128) ? g + 8 : g;    // clamp: harmless reload
            pf[cur] = *(const bf16x8*)(pptr + gp * 32);
            int jg = g * 32 + quad * 8;            // global j base for this lane
            int jl = t * 32 + quad * 8;            // slab-local j for ldsB
            f32x4 iv0 = *(const f32x4*)&lds_inv[jg];
            f32x4 iv1 = *(const f32x4*)&lds_inv[jg + 4];
            bf16x8 afrag;
            f32x4 av0, av1;
            #pragma unroll
            for (int c = 0; c < 8; ++c) {
                float isc = c < 4 ? iv0[c] : iv1[c - 4];
                float attv = (float)pv[c] * isc;
                afrag[c] = (bf16)attv;
                if (c < 4) av0[c] = attv; else av1[c - 4] = attv;
            }
            *(f32x4*)(aptr + g * 32) = av0;
            *(f32x4*)(aptr + g * 32 + 4) = av1;
            #pragma unroll
            for (int ft = 0; ft < 4; ++ft) {
                bf16x8 bfrag = *(const bf16x8*)&ldsB[(ft * 16 + n16) * BSTRIDE + jl];
                acc[ft] = __builtin_amdgcn_mfma_f32_16x16x32_bf16(afrag, bfrag, acc[ft], 0, 0, 0);
            }
        }
    }
    // epilogue: full row sums -> elu -> out. C/D layout: col=lane&15, row=quad*4+reg.
    #pragma unroll
    for (int ft = 0; ft < 4; ++ft) {
        #pragma unroll
        for (int r = 0; r < 4; ++r) {
            int row_l = quad * 4 + r;
            int i_g = itile * 64 + wave * 16 + row_l;
            float v = acc[ft][r];
            out[(size_t)i_g * (K_CH * OUT_F) + kch * OUT_F + ft * 16 + n16] =
                v > 0.f ? v : __expf(v) - 1.f;
        }
    }
}

extern "C" void kernel_launch(void* const* d_in, const int* in_sizes, int n_in,
                              void* d_out, int out_size, void* d_ws, size_t ws_size,
                              hipStream_t stream) {
    (void)out_size; (void)ws_size;
    const float *h = nullptr, *edge = nullptr, *W = nullptr, *a = nullptr;
    for (int i = 0; i < n_in; ++i) {
        int sz = in_sizes[i];
        if (sz == NN * IN_F)               h    = (const float*)d_in[i];
        else if (sz == K_CH * NN * NN)     edge = (const float*)d_in[i];
        else if (sz == IN_F * OUT_F)       W    = (const float*)d_in[i];
        else if (sz == 2 * OUT_F)          a    = (const float*)d_in[i];
    }

    char* ws = (char*)d_ws;
    size_t off = 0;
    float* Wh      = (float*)(ws + off); off += (size_t)NN * OUT_F * 4;               // 1 MB
    float* Wh1     = (float*)(ws + off); off += NN * 4;                               // 16 KB
    float* Wh2     = (float*)(ws + off); off += NN * 4;                               // 16 KB
    float* s_inv   = (float*)(ws + off); off += (size_t)K_CH * NN * 4;                // 64 KB
    bf16*  WhT     = (bf16*) (ws + off); off += (size_t)OUT_F * NN * 2;               // 512 KB
    float* partial = (float*)(ws + off); off += (size_t)K_CH * IC1 * NN * 4;          // 8.4 MB
    bf16*  p_buf   = (bf16*) (ws + off); off += (size_t)K_CH * NN * NN * 2;           // 134 MB

    float* out_h   = (float*)d_out;
    float* att_out = out_h + (size_t)NN * (K_CH * OUT_F);

    k0_wh<<<dim3(NN / 4), 256, 0, stream>>>(h, W, a, Wh, Wh1, Wh2);
    k0_transpose<<<dim3(NN / 64), 256, 0, stream>>>(Wh, WhT);
    k1_colsum<<<dim3(IC1, 4, K_CH), 256, 0, stream>>>(edge, Wh1, Wh2, p_buf, partial);
    k1_reduce<<<dim3(NN / 64, K_CH), 256, 0, stream>>>(partial, s_inv);
    k2_fused<<<dim3(64, K_CH), 256, 0, stream>>>(p_buf, s_inv, WhT, att_out, out_h);
}

// Round 11
// 566.151 us; speedup vs baseline: 1.1386x; 1.0444x over previous
//
#include <hip/hip_runtime.h>

#define NN 4096
#define IN_F 256
#define OUT_F 64
#define K_CH 4
#define ALPHA 0.2f
#define ROWS1 32       // rows per k1 chunk
#define IC1 128        // NN / ROWS1 chunks per channel
#define BSTRIDE 264    // LDS B-slab row stride (bf16 elems): even 8/bank, 16B-aligned

typedef __bf16 bf16;
typedef __attribute__((ext_vector_type(8))) __bf16 bf16x8;
typedef __attribute__((ext_vector_type(4))) __bf16 bf16x4;
typedef __attribute__((ext_vector_type(4))) float f32x4;

// ---------------- k0: Wh = h@W (fp32) ; Wh1 = Wh@a[:64] ; Wh2 = Wh@a[64:]
__global__ __launch_bounds__(256) void k0_wh(const float* __restrict__ h,
                                             const float* __restrict__ W,
                                             const float* __restrict__ a,
                                             float* __restrict__ Wh,
                                             float* __restrict__ Wh1,
                                             float* __restrict__ Wh2) {
    int tid = threadIdx.x;
    int wave = tid >> 6, lane = tid & 63;
    int i = blockIdx.x * 4 + wave;
    const float* hrow = h + (size_t)i * IN_F;
    float acc = 0.f;
    #pragma unroll 8
    for (int c = 0; c < IN_F; ++c)
        acc += hrow[c] * W[c * OUT_F + lane];
    Wh[(size_t)i * OUT_F + lane] = acc;
    float v1 = acc * a[lane];
    float v2 = acc * a[OUT_F + lane];
    #pragma unroll
    for (int o = 32; o > 0; o >>= 1) {
        v1 += __shfl_xor(v1, o, 64);
        v2 += __shfl_xor(v2, o, 64);
    }
    if (lane == 0) { Wh1[i] = v1; Wh2[i] = v2; }
}

// ---------------- k0T: WhT[f][j] = (bf16)Wh[j][f]   (for MFMA B-fragments)
__global__ __launch_bounds__(256) void k0_transpose(const float* __restrict__ Wh,
                                                    bf16* __restrict__ WhT) {
    __shared__ float lds[OUT_F * 65];
    int tid = threadIdx.x;
    int i0 = blockIdx.x * 64;
    int f = tid & 63;
    int r0 = tid >> 6;
    #pragma unroll
    for (int s = 0; s < 16; ++s) {
        int r = r0 * 16 + s;
        lds[f * 65 + r] = Wh[(size_t)(i0 + r) * OUT_F + f];
    }
    __syncthreads();
    int f2 = tid >> 2;
    int c0 = (tid & 3) * 16;
    #pragma unroll
    for (int s = 0; s < 16; ++s) {
        int c = c0 + s;
        WhT[(size_t)f2 * NN + i0 + c] = (bf16)lds[f2 * 65 + c];
    }
}

// ---------------- k1: the ONLY edge reader. NT loads: edge is read-once, keep it
// OUT of L2/L3 so the freshly written p stays L3-resident for k2.
// p[k][i][j] = bf16(masked exp); partial[k][ic][j] = chunk col sums.
// grid (IC1=128 chunks of 32 rows, 4 jquarter, 4 k) x 256; depth-8 row prefetch.
__global__ __launch_bounds__(256) void k1_colsum(const float* __restrict__ edge,
                                                 const float* __restrict__ Wh1,
                                                 const float* __restrict__ Wh2,
                                                 bf16* __restrict__ p_buf,
                                                 float* __restrict__ partial) {
    int tid = threadIdx.x;
    int kch = blockIdx.z;
    int j0 = blockIdx.y * 1024 + tid * 4;
    int ic = blockIdx.x;
    int ibase = ic * ROWS1;
    f32x4 w2 = *(const f32x4*)&Wh2[j0];
    // hoist all 32 row coefficients up front (uniform -> scalar regs)
    f32x4 w1v[ROWS1 / 4];
    #pragma unroll
    for (int t = 0; t < ROWS1 / 4; ++t)
        w1v[t] = *(const f32x4*)&Wh1[ibase + t * 4];
    f32x4 s = {0.f, 0.f, 0.f, 0.f};
    const float* base = edge + ((size_t)kch * NN + ibase) * NN + j0;
    bf16* pbase = p_buf + ((size_t)kch * NN + ibase) * NN + j0;
    f32x4 r[8];
    #pragma unroll
    for (int t = 0; t < 8; ++t)
        r[t] = __builtin_nontemporal_load((const f32x4*)(base + (size_t)t * NN));
    #pragma unroll
    for (int ii = 0; ii < ROWS1; ++ii) {
        int cur = ii & 7;
        f32x4 e = r[cur];
        int ip = (ii + 8 < ROWS1) ? ii + 8 : ii;   // clamp: harmless reload
        r[cur] = __builtin_nontemporal_load((const f32x4*)(base + (size_t)ip * NN));
        float wh1 = w1v[ii >> 2][ii & 3];
        bf16x4 pv;
        #pragma unroll
        for (int c = 0; c < 4; ++c) {
            float xv = wh1 + w2[c];
            float lk = xv > 0.f ? xv : ALPHA * xv;
            float val = e[c] > 0.f ? __expf(lk * e[c]) : 0.f;
            bf16 vb = (bf16)val;
            pv[c] = vb;
            s[c] += (float)vb;     // sum the ROUNDED value -> consistent softmax
        }
        *(bf16x4*)(pbase + (size_t)ii * NN) = pv;   // plain store: want p in L3
    }
    *(f32x4*)(partial + ((size_t)kch * IC1 + ic) * NN + j0) = s;
}

// ---------------- k1b: s_inv[k][j] = 1 / sum_ic partial[k][ic][j]
__global__ __launch_bounds__(256) void k1_reduce(const float* __restrict__ partial,
                                                 float* __restrict__ s_inv) {
    __shared__ float red[256];
    int tid = threadIdx.x;
    int kch = blockIdx.y;
    int jl = tid & 63, g = tid >> 6;
    int j = blockIdx.x * 64 + jl;
    const float* pb = partial + (size_t)kch * IC1 * NN;
    float s = 0.f;
    #pragma unroll 8
    for (int t = 0; t < IC1 / 4; ++t)
        s += pb[(size_t)(g * (IC1 / 4) + t) * NN + j];
    red[tid] = s;
    __syncthreads();
    if (tid < 64) {
        float tot = red[tid] + red[tid + 64] + red[tid + 128] + red[tid + 192];
        s_inv[kch * NN + j] = tot > 0.f ? 1.f / tot : 0.f;
    }
}

// ---------------- k2: FULL-j per block. att = p*inv (write) + acc = att @ Wh (MFMA),
// then elu(acc) -> out directly. No hp buffer, no k3.
// grid (64 itile, 4 kch) x 256 (4 waves; wave owns 16 rows, all 4096 j).
// B-slabs (64f x 256j) re-staged in LDS per slab; depth-8 p-prefetch ring runs
// through slab boundaries (p is j-linear, now L3-hot thanks to k1's NT edge loads).
// Wave layout = mfma_f32_16x16x32_bf16 A-fragment (row i = lane&15, k = quad*8+c).
__global__ __launch_bounds__(256) void k2_fused(const bf16* __restrict__ p_buf,
                                                const float* __restrict__ s_inv,
                                                const bf16* __restrict__ WhT,
                                                float* __restrict__ att_out,
                                                float* __restrict__ out) {
    __shared__ bf16 ldsB[OUT_F * BSTRIDE];
    __shared__ float lds_inv[NN];
    int tid = threadIdx.x;
    int itile = blockIdx.x;
    int kch = blockIdx.y;
    // stage inv_s for ALL j once (16 KB)
    #pragma unroll
    for (int t = 0; t < NN / 256; ++t)
        lds_inv[t * 256 + tid] = s_inv[kch * NN + t * 256 + tid];
    int wave = tid >> 6, lane = tid & 63;
    int n16 = lane & 15, quad = lane >> 4;
    int i_row = itile * 64 + wave * 16 + n16;
    const size_t ebase = ((size_t)kch * NN + i_row) * NN + quad * 8;
    const bf16* pptr = p_buf + ebase;
    float* aptr = att_out + ebase;
    f32x4 acc[4] = {};
    // depth-8 prefetch ring over 128 global steps (32 j per step)
    bf16x8 pf[8];
    #pragma unroll
    for (int t = 0; t < 8; ++t)
        pf[t] = *(const bf16x8*)(pptr + t * 32);
    int f = tid >> 2, part = (tid & 3) * 64;
    const bf16* wsrc = WhT + (size_t)f * NN + part;
    for (int slab = 0; slab < 16; ++slab) {
        __syncthreads();   // protect ldsB from previous slab's readers
        #pragma unroll
        for (int u = 0; u < 8; ++u) {
            bf16x8 v = *(const bf16x8*)(wsrc + slab * 256 + u * 8);
            *(bf16x8*)&ldsB[f * BSTRIDE + part + u * 8] = v;
        }
        __syncthreads();
        #pragma unroll
        for (int t = 0; t < 8; ++t) {
            int g = slab * 8 + t;
            int cur = g & 7;
            bf16x8 pv = pf[cur];
            int gp = (g + 8 < 128) ? g + 8 : g;    // clamp: harmless reload
            pf[cur] = *(const bf16x8*)(pptr + gp * 32);
            int jg = g * 32 + quad * 8;            // global j base for this lane
            int jl = t * 32 + quad * 8;            // slab-local j for ldsB
            f32x4 iv0 = *(const f32x4*)&lds_inv[jg];
            f32x4 iv1 = *(const f32x4*)&lds_inv[jg + 4];
            bf16x8 afrag;
            f32x4 av0, av1;
            #pragma unroll
            for (int c = 0; c < 8; ++c) {
                float isc = c < 4 ? iv0[c] : iv1[c - 4];
                float attv = (float)pv[c] * isc;
                afrag[c] = (bf16)attv;
                if (c < 4) av0[c] = attv; else av1[c - 4] = attv;
            }
            *(f32x4*)(aptr + g * 32) = av0;
            *(f32x4*)(aptr + g * 32 + 4) = av1;
            #pragma unroll
            for (int ft = 0; ft < 4; ++ft) {
                bf16x8 bfrag = *(const bf16x8*)&ldsB[(ft * 16 + n16) * BSTRIDE + jl];
                acc[ft] = __builtin_amdgcn_mfma_f32_16x16x32_bf16(afrag, bfrag, acc[ft], 0, 0, 0);
            }
        }
    }
    // epilogue: full row sums -> elu -> out. C/D layout: col=lane&15, row=quad*4+reg.
    #pragma unroll
    for (int ft = 0; ft < 4; ++ft) {
        #pragma unroll
        for (int r = 0; r < 4; ++r) {
            int row_l = quad * 4 + r;
            int i_g = itile * 64 + wave * 16 + row_l;
            float v = acc[ft][r];
            out[(size_t)i_g * (K_CH * OUT_F) + kch * OUT_F + ft * 16 + n16] =
                v > 0.f ? v : __expf(v) - 1.f;
        }
    }
}

extern "C" void kernel_launch(void* const* d_in, const int* in_sizes, int n_in,
                              void* d_out, int out_size, void* d_ws, size_t ws_size,
                              hipStream_t stream) {
    (void)out_size; (void)ws_size;
    const float *h = nullptr, *edge = nullptr, *W = nullptr, *a = nullptr;
    for (int i = 0; i < n_in; ++i) {
        int sz = in_sizes[i];
        if (sz == NN * IN_F)               h    = (const float*)d_in[i];
        else if (sz == K_CH * NN * NN)     edge = (const float*)d_in[i];
        else if (sz == IN_F * OUT_F)       W    = (const float*)d_in[i];
        else if (sz == 2 * OUT_F)          a    = (const float*)d_in[i];
    }

    char* ws = (char*)d_ws;
    size_t off = 0;
    float* Wh      = (float*)(ws + off); off += (size_t)NN * OUT_F * 4;               // 1 MB
    float* Wh1     = (float*)(ws + off); off += NN * 4;                               // 16 KB
    float* Wh2     = (float*)(ws + off); off += NN * 4;                               // 16 KB
    float* s_inv   = (float*)(ws + off); off += (size_t)K_CH * NN * 4;                // 64 KB
    bf16*  WhT     = (bf16*) (ws + off); off += (size_t)OUT_F * NN * 2;               // 512 KB
    float* partial = (float*)(ws + off); off += (size_t)K_CH * IC1 * NN * 4;          // 8.4 MB
    bf16*  p_buf   = (bf16*) (ws + off); off += (size_t)K_CH * NN * NN * 2;           // 134 MB

    float* out_h   = (float*)d_out;
    float* att_out = out_h + (size_t)NN * (K_CH * OUT_F);

    k0_wh<<<dim3(NN / 4), 256, 0, stream>>>(h, W, a, Wh, Wh1, Wh2);
    k0_transpose<<<dim3(NN / 64), 256, 0, stream>>>(Wh, WhT);
    k1_colsum<<<dim3(IC1, 4, K_CH), 256, 0, stream>>>(edge, Wh1, Wh2, p_buf, partial);
    k1_reduce<<<dim3(NN / 64, K_CH), 256, 0, stream>>>(partial, s_inv);
    k2_fused<<<dim3(64, K_CH), 256, 0, stream>>>(p_buf, s_inv, WhT, att_out, out_h);
}